// Round 3
// baseline (668.868 us; speedup 1.0000x reference)
//
#include <hip/hip_runtime.h>

typedef __bf16 bf16;
typedef __bf16 bf16x8 __attribute__((ext_vector_type(8)));
typedef __bf16 bf16x4 __attribute__((ext_vector_type(4)));
typedef float  f32x4  __attribute__((ext_vector_type(4)));

#define BATCH   16
#define CDIM    512
#define NSPAT   4096
#define QKV_M   1536
#define INNER   512

// async global->LDS, 16B per lane; LDS dest = wave-uniform base + lane*16
__device__ __forceinline__ void gld16(const bf16* g, const bf16* l) {
  __builtin_amdgcn_global_load_lds(
      (const __attribute__((address_space(1))) void*)g,
      (__attribute__((address_space(3))) void*)l, 16, 0, 0);
}

// ---------------------------------------------------------------------------
__global__ __launch_bounds__(256) void cast_f32_bf16_kernel(
    const float* __restrict__ in, bf16* __restrict__ out, int n4) {
  int i = blockIdx.x * 256 + threadIdx.x;
  if (i >= n4) return;
  float4 v = ((const float4*)in)[i];
  bf16x4 o = { (bf16)v.x, (bf16)v.y, (bf16)v.z, (bf16)v.w };
  *(bf16x4*)(out + (size_t)i * 4) = o;
}

// ---------------------------------------------------------------------------
// x (B, C=512, N=4096) f32 -> xt (B, N, C) bf16   (64x64 LDS tile transpose)
// ---------------------------------------------------------------------------
__global__ __launch_bounds__(256) void transpose_cast_kernel(
    const float* __restrict__ x, bf16* __restrict__ xt) {
  __shared__ __attribute__((aligned(16))) bf16 T[64][72];
  int b = blockIdx.z, c0 = blockIdx.y * 64, n0 = blockIdx.x * 64;
  int t = threadIdx.x;
  const float* xp = x + ((size_t)b * CDIM + c0) * NSPAT + n0;
#pragma unroll
  for (int i = 0; i < 4; ++i) {
    int v = t + i * 256;
    int c = v >> 4, nq = (v & 15) * 4;
    float4 rd = *(const float4*)(xp + (size_t)c * NSPAT + nq);
    T[nq + 0][c] = (bf16)rd.x; T[nq + 1][c] = (bf16)rd.y;
    T[nq + 2][c] = (bf16)rd.z; T[nq + 3][c] = (bf16)rd.w;
  }
  __syncthreads();
  bf16* op = xt + ((size_t)b * NSPAT + n0) * CDIM + c0;
#pragma unroll
  for (int i = 0; i < 2; ++i) {
    int v = t + i * 256;
    int n = v >> 3, cc = (v & 7) * 8;
    *(bf16x8*)(op + (size_t)n * CDIM + cc) = *(const bf16x8*)&T[n][cc];
  }
}

// ---------------------------------------------------------------------------
// GEMM: C[b] = A(M,K) * Bt[b](N,K)^T, k-contiguous operands, glds staging.
// Packed vector epilogues via MFMA operand-order choice (no LDS, no scalar
// stores):
//  OUTMODE 0, m0<1024 (Q/K): swapped mfma -> in-lane 4 consecutive n ->
//      bf16x4 stores to qkv (b, m<1024, n).
//  OUTMODE 0, m0>=1024 (V): normal mfma -> in-lane 4 consecutive m(=e) ->
//      bf16x4 stores to vT (b, n, e).
//  OUTMODE 1: swapped mfma -> float4 stores + bias + LN partial sums.
// ---------------------------------------------------------------------------
template <int OUTMODE>
__global__ __launch_bounds__(256) void gemm_tn_kernel(
    const bf16* __restrict__ A, const bf16* __restrict__ Bt,
    void* __restrict__ Cout, const float* __restrict__ bias,
    float* __restrict__ part, bf16* __restrict__ vT,
    int M, int N, int K) {
  __shared__ __attribute__((aligned(16))) bf16 smem[8192];  // As[4096] ++ Bs[4096]

  int b  = blockIdx.z;
  int m0 = blockIdx.y * 128, n0 = blockIdx.x * 128;
  const bf16* Ab = A + (size_t)m0 * K;
  const bf16* Bb = Bt + ((size_t)b * N + n0) * K;

  int tid = threadIdx.x, lane = tid & 63, wid = tid >> 6;
  int wm = wid >> 1, wn = wid & 1, lm = lane & 15, kqd = lane >> 4;
  int srow = lane >> 2, skb = lane & 3;
  const bool vmode = (OUTMODE == 0) && (m0 >= 1024);

  f32x4 acc[4][4] = {};

  for (int k0 = 0; k0 < K; k0 += 32) {
#pragma unroll
    for (int i = 0; i < 2; ++i) {
      int gi = wid * 2 + i;
      gld16(Ab + (size_t)(gi * 16 + srow) * K + k0 + skb * 8, smem + gi * 512);
      gld16(Bb + (size_t)(gi * 16 + srow) * K + k0 + skb * 8, smem + 4096 + gi * 512);
    }
    __syncthreads();
    bf16x8 af[4], bfr[4];
#pragma unroll
    for (int im = 0; im < 4; ++im)
      af[im] = *(const bf16x8*)&smem[(wm * 64 + im * 16 + lm) * 32 + kqd * 8];
#pragma unroll
    for (int in = 0; in < 4; ++in)
      bfr[in] = *(const bf16x8*)&smem[4096 + (wn * 64 + in * 16 + lm) * 32 + kqd * 8];
    if (vmode) {
      // rows = m (in-lane), cols = n (lane)
#pragma unroll
      for (int im = 0; im < 4; ++im)
#pragma unroll
        for (int in = 0; in < 4; ++in)
          acc[im][in] = __builtin_amdgcn_mfma_f32_16x16x32_bf16(af[im], bfr[in], acc[im][in], 0, 0, 0);
    } else {
      // swapped: rows = n (in-lane), cols = m (lane)
#pragma unroll
      for (int in = 0; in < 4; ++in)
#pragma unroll
        for (int im = 0; im < 4; ++im)
          acc[in][im] = __builtin_amdgcn_mfma_f32_16x16x32_bf16(bfr[in], af[im], acc[in][im], 0, 0, 0);
    }
    __syncthreads();
  }

  if (OUTMODE == 0) {
    if (!vmode) {
      // Q/K: store bf16x4 of 4 consecutive n at row m
      bf16* C = (bf16*)Cout + (size_t)b * 1024 * N;
#pragma unroll
      for (int in = 0; in < 4; ++in)
#pragma unroll
        for (int im = 0; im < 4; ++im) {
          int m  = m0 + wm * 64 + im * 16 + lm;
          int nb = n0 + wn * 64 + in * 16 + kqd * 4;
          bf16x4 o = { (bf16)acc[in][im][0], (bf16)acc[in][im][1],
                       (bf16)acc[in][im][2], (bf16)acc[in][im][3] };
          *(bf16x4*)(C + (size_t)m * N + nb) = o;
        }
    } else {
      // V: store bf16x4 of 4 consecutive e at row n of vT (b, n, 512)
      bf16* Vt = vT + (size_t)b * N * 512;
#pragma unroll
      for (int im = 0; im < 4; ++im)
#pragma unroll
        for (int in = 0; in < 4; ++in) {
          int e = (m0 - 1024) + wm * 64 + im * 16 + kqd * 4;
          int n = n0 + wn * 64 + in * 16 + lm;
          bf16x4 o = { (bf16)acc[im][in][0], (bf16)acc[im][in][1],
                       (bf16)acc[im][in][2], (bf16)acc[im][in][3] };
          *(bf16x4*)(Vt + (size_t)n * 512 + e) = o;
        }
    }
  } else {
    float* C = (float*)Cout + (size_t)b * M * N;
    float s = 0.f, s2 = 0.f;
#pragma unroll
    for (int in = 0; in < 4; ++in)
#pragma unroll
      for (int im = 0; im < 4; ++im) {
        int m  = m0 + wm * 64 + im * 16 + lm;
        int nb = n0 + wn * 64 + in * 16 + kqd * 4;
        float bv = bias[m];
        float4 o;
        o.x = acc[in][im][0] + bv; o.y = acc[in][im][1] + bv;
        o.z = acc[in][im][2] + bv; o.w = acc[in][im][3] + bv;
        *(float4*)(C + (size_t)m * N + nb) = o;
        s += o.x + o.y + o.z + o.w;
        s2 += o.x * o.x + o.y * o.y + o.z * o.z + o.w * o.w;
      }
#pragma unroll
    for (int off = 32; off > 0; off >>= 1) {
      s  += __shfl_down(s, off, 64);
      s2 += __shfl_down(s2, off, 64);
    }
    __shared__ float red[8];
    if (lane == 0) { red[wid] = s; red[wid + 4] = s2; }
    __syncthreads();
    if (tid == 0) {
      atomicAdd(&part[b * 2],     red[0] + red[1] + red[2] + red[3]);
      atomicAdd(&part[b * 2 + 1], red[4] + red[5] + red[6] + red[7]);
    }
  }
}

// ---------------------------------------------------------------------------
// Scores, chunked partials: sc_part[bh][chunk][d][e] = sum_{n chunk} q k.
// No LDS, no barriers: all fragments direct 16B global loads (64B segments).
// ---------------------------------------------------------------------------
__global__ __launch_bounds__(256) void attn_scores_kernel(
    const bf16* __restrict__ qkv, float* __restrict__ sc_part) {
  int chunk = blockIdx.x, bh = blockIdx.y, b = bh >> 3, h = bh & 7;
  const bf16* q = qkv + ((size_t)b * 1024 + h * 64) * NSPAT + chunk * 512;
  const bf16* k = q + (size_t)512 * NSPAT;

  int tid = threadIdx.x, lane = tid & 63, wid = tid >> 6;
  int lm = lane & 15, kqd = lane >> 4, d0 = wid * 16;

  f32x4 acc[4] = {};
#pragma unroll 2
  for (int n0 = 0; n0 < 512; n0 += 32) {
    bf16x8 a = *(const bf16x8*)(q + (size_t)(d0 + lm) * NSPAT + n0 + kqd * 8);
#pragma unroll
    for (int eb = 0; eb < 4; ++eb) {
      bf16x8 bb = *(const bf16x8*)(k + (size_t)(eb * 16 + lm) * NSPAT + n0 + kqd * 8);
      acc[eb] = __builtin_amdgcn_mfma_f32_16x16x32_bf16(a, bb, acc[eb], 0, 0, 0);
    }
  }
  float* outp = sc_part + ((size_t)bh * 8 + chunk) * 4096;
#pragma unroll
  for (int eb = 0; eb < 4; ++eb)
#pragma unroll
    for (int r = 0; r < 4; ++r)
      outp[(d0 + kqd * 4 + r) * 64 + eb * 16 + lm] = acc[eb][r];
}

// ---------------------------------------------------------------------------
// Softmax: sum 8 partial chunks, scale 1/8, softmax rows -> bf16 attn (d,e)
// ---------------------------------------------------------------------------
__global__ __launch_bounds__(256) void attn_softmax_kernel(
    const float* __restrict__ sc_part, bf16* __restrict__ attn_w) {
  __shared__ float ssum[64][65];
  int bh = blockIdx.x, t = threadIdx.x;
  const float* p = sc_part + (size_t)bh * 8 * 4096;
  float v[16];
#pragma unroll
  for (int j = 0; j < 16; ++j) v[j] = p[t + j * 256];
  for (int c = 1; c < 8; ++c)
#pragma unroll
    for (int j = 0; j < 16; ++j) v[j] += p[c * 4096 + t + j * 256];
#pragma unroll
  for (int j = 0; j < 16; ++j) {
    int q = t + j * 256;
    ssum[q >> 6][q & 63] = v[j];
  }
  __syncthreads();
  if (t < 64) {
    float mx = -1e30f;
    for (int e = 0; e < 64; ++e) mx = fmaxf(mx, ssum[t][e]);
    float s = 0.f;
    for (int e = 0; e < 64; ++e) {
      float ex = __expf((ssum[t][e] - mx) * 0.125f);
      ssum[t][e] = ex; s += ex;
    }
    float inv = 1.0f / s;
    bf16* ow = attn_w + (size_t)bh * 4096 + t * 64;
    for (int e = 0; e < 64; ++e) ow[e] = (bf16)(ssum[t][e] * inv);
  }
}

// ---------------------------------------------------------------------------
// PV: O^T(b, n, c) slice [h*64..h*64+64) = (attn(d,e) x vT(n,e)^T)^T.
// A = attn (k=e contig), B = vT (k=e contig); all direct global frags.
// In-lane 4 consecutive d -> bf16x4 stores into O^T rows.
// grid (16 n-chunks of 256, 128 bh); each wave owns 64 n.
// ---------------------------------------------------------------------------
__global__ __launch_bounds__(256) void attn_pv_kernel(
    const bf16* __restrict__ vT, const bf16* __restrict__ attn_w,
    bf16* __restrict__ attn_t) {
  int bh = blockIdx.y, b = bh >> 3, h = bh & 7;
  int tid = threadIdx.x, lane = tid & 63, wid = tid >> 6;
  int lm = lane & 15, kqd = lane >> 4;
  int nbase = blockIdx.x * 256 + wid * 64;

  const bf16* aw = attn_w + (size_t)bh * 4096;
  const bf16* vp = vT + ((size_t)b * NSPAT) * 512 + h * 64;
  bf16* op = attn_t + ((size_t)b * NSPAT) * 512 + h * 64;

  bf16x8 af[4][2];
#pragma unroll
  for (int im = 0; im < 4; ++im)
#pragma unroll
    for (int hf = 0; hf < 2; ++hf)
      af[im][hf] = *(const bf16x8*)(aw + (im * 16 + lm) * 64 + hf * 32 + kqd * 8);

#pragma unroll
  for (int nt = 0; nt < 4; ++nt) {
    int n = nbase + nt * 16 + lm;
    bf16x8 b0 = *(const bf16x8*)(vp + (size_t)n * 512 + kqd * 8);
    bf16x8 b1 = *(const bf16x8*)(vp + (size_t)n * 512 + 32 + kqd * 8);
    f32x4 o[4] = {};
#pragma unroll
    for (int im = 0; im < 4; ++im) {
      o[im] = __builtin_amdgcn_mfma_f32_16x16x32_bf16(af[im][0], b0, o[im], 0, 0, 0);
      o[im] = __builtin_amdgcn_mfma_f32_16x16x32_bf16(af[im][1], b1, o[im], 0, 0, 0);
    }
    // store: in-lane 4 consecutive d; row n = lane-derived
#pragma unroll
    for (int im = 0; im < 4; ++im) {
      int nn = nbase + nt * 16 + lm;
      int d  = im * 16 + kqd * 4;
      bf16x4 ov = { (bf16)o[im][0], (bf16)o[im][1], (bf16)o[im][2], (bf16)o[im][3] };
      *(bf16x4*)(op + (size_t)nn * 512 + d) = ov;
    }
  }
}

// ---------------------------------------------------------------------------
__global__ void ln_stats_kernel(const float* __restrict__ part, float2* __restrict__ stats) {
  int b = threadIdx.x;
  if (b < 16) {
    const float invn = 1.0f / 2097152.0f;
    float mean = part[b * 2] * invn;
    float var  = part[b * 2 + 1] * invn - mean * mean;
    stats[b] = make_float2(mean, rsqrtf(var + 1e-5f));
  }
}

__global__ __launch_bounds__(256) void ln_apply_kernel(
    float* __restrict__ out, const float2* __restrict__ stats,
    const float* __restrict__ gamma, const float* __restrict__ beta) {
  size_t i4 = (size_t)blockIdx.x * 256 + threadIdx.x;
  size_t e  = i4 * 4;
  int b = (int)(e >> 21);
  int c = (int)((e >> 12) & 511);
  float2 st = stats[b];
  float g  = gamma[c] * st.y;
  float bb = beta[c] - st.x * g;
  float4* p = (float4*)out;
  float4 v = p[i4];
  v.x = v.x * g + bb; v.y = v.y * g + bb; v.z = v.z * g + bb; v.w = v.w * g + bb;
  p[i4] = v;
}

// ---------------------------------------------------------------------------
extern "C" void kernel_launch(void* const* d_in, const int* in_sizes, int n_in,
                              void* d_out, int out_size, void* d_ws, size_t ws_size,
                              hipStream_t stream) {
  const float* x      = (const float*)d_in[0];
  const float* w_qkv  = (const float*)d_in[1];
  const float* w_out  = (const float*)d_in[2];
  const float* b_out  = (const float*)d_in[3];
  const float* gamma  = (const float*)d_in[4];
  const float* beta   = (const float*)d_in[5];
  float* out = (float*)d_out;

  char* ws = (char*)d_ws;
  bf16*   xt      = (bf16*)(ws);                    // 64 MiB (B, N, C); dead after QKV gemm
  float*  sc_part = (float*)(ws);                   // 16 MiB overlay
  bf16*   attn_w  = (bf16*)(ws + 16777216);         //  1 MiB overlay
  bf16*   wqkvb   = (bf16*)(ws + 67108864);         // 1.5 MiB
  bf16*   woutb   = (bf16*)(ws + 68681728);         // 0.5 MiB
  bf16*   qkvb    = (bf16*)(ws + 69206016);         // 128 MiB (B, 1024, N): Q,K
  bf16*   vTb     = (bf16*)(ws + 203423744);        //  64 MiB (B, N, 512): V^T
  bf16*   attn_t  = (bf16*)(ws + 270532608);        //  64 MiB (B, N, C): O^T
  float*  part    = (float*)(ws + 337641472);       // 32 f32
  float2* stats   = (float2*)(ws + 337641600);      // 16 float2

  hipMemsetAsync(part, 0, 128, stream);

  transpose_cast_kernel<<<dim3(64, 8, BATCH), 256, 0, stream>>>(x, xt);
  cast_f32_bf16_kernel<<<768, 256, 0, stream>>>(w_qkv, wqkvb, 196608);
  cast_f32_bf16_kernel<<<256, 256, 0, stream>>>(w_out, woutb, 65536);

  // QKV projection -> Q,K (b,1024,n) + V^T (b,n,512)
  gemm_tn_kernel<0><<<dim3(32, 12, BATCH), 256, 0, stream>>>(
      wqkvb, xt, (void*)qkvb, nullptr, nullptr, vTb, QKV_M, NSPAT, CDIM);

  // channel attention
  attn_scores_kernel<<<dim3(8, 128), 256, 0, stream>>>(qkvb, sc_part);
  attn_softmax_kernel<<<128, 256, 0, stream>>>(sc_part, attn_w);
  attn_pv_kernel<<<dim3(16, 128), 256, 0, stream>>>(vTb, attn_w, attn_t);

  // output projection + bias + LN partials -> d_out f32
  gemm_tn_kernel<1><<<dim3(32, 4, BATCH), 256, 0, stream>>>(
      woutb, attn_t, (void*)out, b_out, part, nullptr, INNER, NSPAT, CDIM);

  ln_stats_kernel<<<1, 16, 0, stream>>>(part, stats);
  ln_apply_kernel<<<32768, 256, 0, stream>>>(out, stats, gamma, beta);
}

// Round 4
// 586.526 us; speedup vs baseline: 1.1404x; 1.1404x over previous
//
#include <hip/hip_runtime.h>

typedef __bf16 bf16;
typedef __bf16 bf16x8 __attribute__((ext_vector_type(8)));
typedef __bf16 bf16x4 __attribute__((ext_vector_type(4)));
typedef float  f32x4  __attribute__((ext_vector_type(4)));

#define BATCH   16
#define CDIM    512
#define NSPAT   4096
#define QKV_M   1536
#define INNER   512

// async global->LDS, 16B per lane; LDS dest = wave-uniform base + lane*16
__device__ __forceinline__ void gld16(const bf16* g, const bf16* l) {
  __builtin_amdgcn_global_load_lds(
      (const __attribute__((address_space(1))) void*)g,
      (__attribute__((address_space(3))) void*)l, 16, 0, 0);
}

// ---------------------------------------------------------------------------
__global__ __launch_bounds__(256) void cast_f32_bf16_kernel(
    const float* __restrict__ in, bf16* __restrict__ out, int n4) {
  int i = blockIdx.x * 256 + threadIdx.x;
  if (i >= n4) return;
  float4 v = ((const float4*)in)[i];
  bf16x4 o = { (bf16)v.x, (bf16)v.y, (bf16)v.z, (bf16)v.w };
  *(bf16x4*)(out + (size_t)i * 4) = o;
}

// ---------------------------------------------------------------------------
// x (B, C=512, N=4096) f32 -> xt (B, N, C) bf16   (64x64 LDS tile transpose)
// ---------------------------------------------------------------------------
__global__ __launch_bounds__(256) void transpose_cast_kernel(
    const float* __restrict__ x, bf16* __restrict__ xt) {
  __shared__ __attribute__((aligned(16))) bf16 T[64][72];
  int b = blockIdx.z, c0 = blockIdx.y * 64, n0 = blockIdx.x * 64;
  int t = threadIdx.x;
  const float* xp = x + ((size_t)b * CDIM + c0) * NSPAT + n0;
#pragma unroll
  for (int i = 0; i < 4; ++i) {
    int v = t + i * 256;
    int c = v >> 4, nq = (v & 15) * 4;
    float4 rd = *(const float4*)(xp + (size_t)c * NSPAT + nq);
    T[nq + 0][c] = (bf16)rd.x; T[nq + 1][c] = (bf16)rd.y;
    T[nq + 2][c] = (bf16)rd.z; T[nq + 3][c] = (bf16)rd.w;
  }
  __syncthreads();
  bf16* op = xt + ((size_t)b * NSPAT + n0) * CDIM + c0;
#pragma unroll
  for (int i = 0; i < 2; ++i) {
    int v = t + i * 256;
    int n = v >> 3, cc = (v & 7) * 8;
    *(bf16x8*)(op + (size_t)n * CDIM + cc) = *(const bf16x8*)&T[n][cc];
  }
}

// ---------------------------------------------------------------------------
// GEMM: C[b] = A(M,K) * Bt[b](N,K)^T, k-contiguous, glds staging, swapped
// mfma (in-lane dim = n).
//  OUTMODE 0 (bf16): pack bf16x4 -> ds_write_b64 into per-wave [m][64] tile
//      (stride 72 shorts: write banks uniform 4/bank = minimum, read banks
//      uniform 8/bank = minimum) -> b128 reads -> 128B-coalesced b128 stores.
//  OUTMODE 1 (f32): direct float4 stores (64B segments) + bias + LN partials.
// ---------------------------------------------------------------------------
template <int OUTMODE>
__global__ __launch_bounds__(256) void gemm_tn_kernel(
    const bf16* __restrict__ A, const bf16* __restrict__ Bt,
    void* __restrict__ Cout, const float* __restrict__ bias,
    float* __restrict__ part, int M, int N, int K) {
  // staging: As[0..4096) ++ Bs[4096..8192); epilogue: 4 waves x 32x72 = 9216
  __shared__ __attribute__((aligned(16))) bf16 smem[9216];

  int b  = blockIdx.z;
  int m0 = blockIdx.y * 128, n0 = blockIdx.x * 128;
  const bf16* Ab = A + (size_t)m0 * K;
  const bf16* Bb = Bt + ((size_t)b * N + n0) * K;

  int tid = threadIdx.x, lane = tid & 63, wid = tid >> 6;
  int wm = wid >> 1, wn = wid & 1, lm = lane & 15, kqd = lane >> 4;
  int srow = lane >> 2, skb = lane & 3;

  f32x4 acc[4][4] = {};   // acc[in][im]: in-lane = 4 consecutive n

  for (int k0 = 0; k0 < K; k0 += 32) {
#pragma unroll
    for (int i = 0; i < 2; ++i) {
      int gi = wid * 2 + i;
      gld16(Ab + (size_t)(gi * 16 + srow) * K + k0 + skb * 8, smem + gi * 512);
      gld16(Bb + (size_t)(gi * 16 + srow) * K + k0 + skb * 8, smem + 4096 + gi * 512);
    }
    __syncthreads();
    bf16x8 af[4], bfr[4];
#pragma unroll
    for (int im = 0; im < 4; ++im)
      af[im] = *(const bf16x8*)&smem[(wm * 64 + im * 16 + lm) * 32 + kqd * 8];
#pragma unroll
    for (int in = 0; in < 4; ++in)
      bfr[in] = *(const bf16x8*)&smem[4096 + (wn * 64 + in * 16 + lm) * 32 + kqd * 8];
#pragma unroll
    for (int in = 0; in < 4; ++in)
#pragma unroll
      for (int im = 0; im < 4; ++im)
        acc[in][im] = __builtin_amdgcn_mfma_f32_16x16x32_bf16(bfr[in], af[im], acc[in][im], 0, 0, 0);
    __syncthreads();
  }

  if (OUTMODE == 0) {
    bf16* C = (bf16*)Cout + (size_t)b * M * N;
    bf16* Ws = smem + wid * 2304;   // per-wave 32 rows x 72 shorts
#pragma unroll
    for (int half = 0; half < 2; ++half) {
#pragma unroll
      for (int imh = 0; imh < 2; ++imh) {
        int im = half * 2 + imh;
        int mloc = imh * 16 + lm;
#pragma unroll
        for (int in = 0; in < 4; ++in) {
          bf16x4 o = { (bf16)acc[in][im][0], (bf16)acc[in][im][1],
                       (bf16)acc[in][im][2], (bf16)acc[in][im][3] };
          *(bf16x4*)&Ws[mloc * 72 + in * 16 + kqd * 4] = o;
        }
      }
      asm volatile("s_waitcnt lgkmcnt(0)");   // same-wave LDS WAR/RAW fence
#pragma unroll
      for (int j = 0; j < 4; ++j) {
        int u = j * 64 + lane;
        int row = u >> 3, cu = (u & 7) * 8;
        *(bf16x8*)(C + (size_t)(m0 + wm * 64 + half * 32 + row) * N + n0 + wn * 64 + cu) =
            *(const bf16x8*)&Ws[row * 72 + cu];
      }
      asm volatile("s_waitcnt lgkmcnt(0)");
    }
  } else {
    float* C = (float*)Cout + (size_t)b * M * N;
    float s = 0.f, s2 = 0.f;
#pragma unroll
    for (int in = 0; in < 4; ++in)
#pragma unroll
      for (int im = 0; im < 4; ++im) {
        int m  = m0 + wm * 64 + im * 16 + lm;
        int nb = n0 + wn * 64 + in * 16 + kqd * 4;
        float bv = bias[m];
        float4 o;
        o.x = acc[in][im][0] + bv; o.y = acc[in][im][1] + bv;
        o.z = acc[in][im][2] + bv; o.w = acc[in][im][3] + bv;
        *(float4*)(C + (size_t)m * N + nb) = o;
        s  += o.x + o.y + o.z + o.w;
        s2 += o.x * o.x + o.y * o.y + o.z * o.z + o.w * o.w;
      }
#pragma unroll
    for (int off = 32; off > 0; off >>= 1) {
      s  += __shfl_down(s, off, 64);
      s2 += __shfl_down(s2, off, 64);
    }
    __shared__ float red[8];
    if (lane == 0) { red[wid] = s; red[wid + 4] = s2; }
    __syncthreads();
    if (tid == 0) {
      atomicAdd(&part[b * 2],     red[0] + red[1] + red[2] + red[3]);
      atomicAdd(&part[b * 2 + 1], red[4] + red[5] + red[6] + red[7]);
    }
  }
}

// ---------------------------------------------------------------------------
// Scores, chunked partials: sc_part[bh][chunk][d][e] = sum_{n chunk} q k.
// No LDS, no barriers; fragments via direct 16B global loads (64B segments).
// ---------------------------------------------------------------------------
__global__ __launch_bounds__(256) void attn_scores_kernel(
    const bf16* __restrict__ qkv, float* __restrict__ sc_part) {
  int chunk = blockIdx.x, bh = blockIdx.y, b = bh >> 3, h = bh & 7;
  const bf16* q = qkv + ((size_t)b * QKV_M + h * 64) * NSPAT + chunk * 512;
  const bf16* k = q + (size_t)INNER * NSPAT;

  int tid = threadIdx.x, lane = tid & 63, wid = tid >> 6;
  int lm = lane & 15, kqd = lane >> 4, d0 = wid * 16;

  f32x4 acc[4] = {};
#pragma unroll 2
  for (int n0 = 0; n0 < 512; n0 += 32) {
    bf16x8 a = *(const bf16x8*)(q + (size_t)(d0 + lm) * NSPAT + n0 + kqd * 8);
#pragma unroll
    for (int eb = 0; eb < 4; ++eb) {
      bf16x8 bb = *(const bf16x8*)(k + (size_t)(eb * 16 + lm) * NSPAT + n0 + kqd * 8);
      acc[eb] = __builtin_amdgcn_mfma_f32_16x16x32_bf16(a, bb, acc[eb], 0, 0, 0);
    }
  }
  float* outp = sc_part + ((size_t)bh * 8 + chunk) * 4096;
#pragma unroll
  for (int eb = 0; eb < 4; ++eb)
#pragma unroll
    for (int r = 0; r < 4; ++r)
      outp[(d0 + kqd * 4 + r) * 64 + eb * 16 + lm] = acc[eb][r];
}

// ---------------------------------------------------------------------------
// Softmax: sum 8 partial chunks, scale 1/8, softmax rows -> bf16 attn (d,e)
// ---------------------------------------------------------------------------
__global__ __launch_bounds__(256) void attn_softmax_kernel(
    const float* __restrict__ sc_part, bf16* __restrict__ attn_w) {
  __shared__ float ssum[64][65];
  int bh = blockIdx.x, t = threadIdx.x;
  const float* p = sc_part + (size_t)bh * 8 * 4096;
  float v[16];
#pragma unroll
  for (int j = 0; j < 16; ++j) v[j] = p[t + j * 256];
  for (int c = 1; c < 8; ++c)
#pragma unroll
    for (int j = 0; j < 16; ++j) v[j] += p[c * 4096 + t + j * 256];
#pragma unroll
  for (int j = 0; j < 16; ++j) {
    int q = t + j * 256;
    ssum[q >> 6][q & 63] = v[j];
  }
  __syncthreads();
  if (t < 64) {
    float mx = -1e30f;
    for (int e = 0; e < 64; ++e) mx = fmaxf(mx, ssum[t][e]);
    float s = 0.f;
    for (int e = 0; e < 64; ++e) {
      float ex = __expf((ssum[t][e] - mx) * 0.125f);
      ssum[t][e] = ex; s += ex;
    }
    float inv = 1.0f / s;
    bf16* ow = attn_w + (size_t)bh * 4096 + t * 64;
    for (int e = 0; e < 64; ++e) ow[e] = (bf16)(ssum[t][e] * inv);
  }
}

// ---------------------------------------------------------------------------
// PV: O^T(b,n,c) slice = (attn * v)^T, chunked over n. grid (8, 128).
// V staged transposed in LDS (conflict-free writes), O via LDS -> b128 stores.
// ---------------------------------------------------------------------------
__global__ __launch_bounds__(256) void attn_pv_kernel(
    const bf16* __restrict__ qkv, const bf16* __restrict__ attn_w,
    bf16* __restrict__ attn_t) {
  __shared__ __attribute__((aligned(16))) bf16 aw[64 * 72];
  __shared__ __attribute__((aligned(16))) bf16 Vs[128 * 72];  // reused for O^T
  int chunk = blockIdx.x, bh = blockIdx.y, b = bh >> 3, h = bh & 7;
  const bf16* vmat = qkv + ((size_t)b * QKV_M + 2 * INNER + h * 64) * NSPAT + chunk * 512;
  bf16* outt = attn_t + ((size_t)b * NSPAT + chunk * 512) * INNER + h * 64;

  int tid = threadIdx.x, lane = tid & 63, wid = tid >> 6;
  int lm = lane & 15, kqd = lane >> 4, d0 = wid * 16;

#pragma unroll
  for (int i = 0; i < 2; ++i) {
    int v = tid + i * 256;
    *(bf16x8*)&aw[(v >> 3) * 72 + (v & 7) * 8] = *(const bf16x8*)(attn_w + (size_t)bh * 4096 + v * 8);
  }
  __syncthreads();
  bf16x8 a0 = *(const bf16x8*)&aw[(d0 + lm) * 72 + kqd * 8];
  bf16x8 a1 = *(const bf16x8*)&aw[(d0 + lm) * 72 + 32 + kqd * 8];

  for (int nc = 0; nc < 512; nc += 128) {
    __syncthreads();
#pragma unroll
    for (int i = 0; i < 4; ++i) {
      int v = i * 256 + tid;
      int e = v & 63, nn = (v >> 6) * 8;
      bf16x8 d = *(const bf16x8*)(vmat + (size_t)e * NSPAT + nc + nn);
#pragma unroll
      for (int j = 0; j < 8; ++j) Vs[(nn + j) * 72 + e] = d[j];
    }
    __syncthreads();
    f32x4 o[8];
#pragma unroll
    for (int nt = 0; nt < 8; ++nt) {
      bf16x8 b0 = *(const bf16x8*)&Vs[(nt * 16 + lm) * 72 + kqd * 8];
      bf16x8 b1 = *(const bf16x8*)&Vs[(nt * 16 + lm) * 72 + 32 + kqd * 8];
      o[nt] = (f32x4){0.f, 0.f, 0.f, 0.f};
      o[nt] = __builtin_amdgcn_mfma_f32_16x16x32_bf16(a0, b0, o[nt], 0, 0, 0);
      o[nt] = __builtin_amdgcn_mfma_f32_16x16x32_bf16(a1, b1, o[nt], 0, 0, 0);
    }
    __syncthreads();
#pragma unroll
    for (int nt = 0; nt < 8; ++nt) {
      bf16x4 ov = { (bf16)o[nt][0], (bf16)o[nt][1], (bf16)o[nt][2], (bf16)o[nt][3] };
      *(bf16x4*)&Vs[(nt * 16 + lm) * 72 + d0 + kqd * 4] = ov;
    }
    __syncthreads();
#pragma unroll
    for (int i = 0; i < 4; ++i) {
      int v = i * 256 + tid;
      int n = v >> 3, dc = (v & 7) * 8;
      *(bf16x8*)(outt + (size_t)(nc + n) * INNER + dc) = *(const bf16x8*)&Vs[n * 72 + dc];
    }
  }
}

// ---------------------------------------------------------------------------
__global__ void ln_stats_kernel(const float* __restrict__ part, float2* __restrict__ stats) {
  int b = threadIdx.x;
  if (b < 16) {
    const float invn = 1.0f / 2097152.0f;
    float mean = part[b * 2] * invn;
    float var  = part[b * 2 + 1] * invn - mean * mean;
    stats[b] = make_float2(mean, rsqrtf(var + 1e-5f));
  }
}

__global__ __launch_bounds__(256) void ln_apply_kernel(
    float* __restrict__ out, const float2* __restrict__ stats,
    const float* __restrict__ gamma, const float* __restrict__ beta) {
  size_t i4 = (size_t)blockIdx.x * 256 + threadIdx.x;
  size_t e  = i4 * 4;
  int b = (int)(e >> 21);
  int c = (int)((e >> 12) & 511);
  float2 st = stats[b];
  float g  = gamma[c] * st.y;
  float bb = beta[c] - st.x * g;
  float4* p = (float4*)out;
  float4 v = p[i4];
  v.x = v.x * g + bb; v.y = v.y * g + bb; v.z = v.z * g + bb; v.w = v.w * g + bb;
  p[i4] = v;
}

// ---------------------------------------------------------------------------
extern "C" void kernel_launch(void* const* d_in, const int* in_sizes, int n_in,
                              void* d_out, int out_size, void* d_ws, size_t ws_size,
                              hipStream_t stream) {
  const float* x      = (const float*)d_in[0];
  const float* w_qkv  = (const float*)d_in[1];
  const float* w_out  = (const float*)d_in[2];
  const float* b_out  = (const float*)d_in[3];
  const float* gamma  = (const float*)d_in[4];
  const float* beta   = (const float*)d_in[5];
  float* out = (float*)d_out;

  char* ws = (char*)d_ws;
  bf16*   xt      = (bf16*)(ws);                    // 64 MiB (B,N,C); dead after QKV gemm
  float*  sc_part = (float*)(ws);                   // 16 MiB overlay
  bf16*   attn_w  = (bf16*)(ws + 16777216);         //  1 MiB overlay
  bf16*   wqkvb   = (bf16*)(ws + 67108864);         // 1.5 MiB
  bf16*   woutb   = (bf16*)(ws + 68681728);         // 0.5 MiB
  bf16*   qkvb    = (bf16*)(ws + 69206016);         // 192 MiB (B,1536,N)
  bf16*   attn_t  = (bf16*)(ws + 270532608);        //  64 MiB (B,N,C): O^T
  float*  part    = (float*)(ws + 337641472);       // 32 f32
  float2* stats   = (float2*)(ws + 337641600);      // 16 float2

  hipMemsetAsync(part, 0, 128, stream);

  transpose_cast_kernel<<<dim3(64, 8, BATCH), 256, 0, stream>>>(x, xt);
  cast_f32_bf16_kernel<<<768, 256, 0, stream>>>(w_qkv, wqkvb, 196608);
  cast_f32_bf16_kernel<<<256, 256, 0, stream>>>(w_out, woutb, 65536);

  // QKV projection -> qkvb (b,1536,n)
  gemm_tn_kernel<0><<<dim3(32, 12, BATCH), 256, 0, stream>>>(
      wqkvb, xt, (void*)qkvb, nullptr, nullptr, QKV_M, NSPAT, CDIM);

  // channel attention
  attn_scores_kernel<<<dim3(8, 128), 256, 0, stream>>>(qkvb, sc_part);
  attn_softmax_kernel<<<128, 256, 0, stream>>>(sc_part, attn_w);
  attn_pv_kernel<<<dim3(8, 128), 256, 0, stream>>>(qkvb, attn_w, attn_t);

  // output projection + bias + LN partials -> d_out f32
  gemm_tn_kernel<1><<<dim3(32, 4, BATCH), 256, 0, stream>>>(
      woutb, attn_t, (void*)out, b_out, part, INNER, NSPAT, CDIM);

  ln_stats_kernel<<<1, 16, 0, stream>>>(part, stats);
  ln_apply_kernel<<<32768, 256, 0, stream>>>(out, stats, gamma, beta);
}